// Round 5
// baseline (3301.600 us; speedup 1.0000x reference)
//
#include <hip/hip_runtime.h>
#include <hip/hip_bf16.h>

// Sizes (fixed by the reference)
#define BN  256
#define SN  512
#define INN 64
#define HN  256
#define MN  64

// LDS strides (f16 elems). All ≡ 4 words mod 32 -> rows 8-15 get a 16-B XOR swizzle.
#define ZINS 328   // zin: [x(64) | h(256)] + 8 pad
#define ZBS  264   // z0/z1: 256 + 8
#define CFS  72    // cfc: 64 + 8
#define HTS  33    // htmp row stride (f32)

// Output offsets (f32 elements)
#define OFF_ACT  393216
#define OFF_CONF 524288
#define OFF_HN   655360

#define FLAG_STRIDE 32        // u32 per flag slot (128 B line spacing)
#define FLAG_BYTES  16384     // 16 groups * 8 blocks * 128 B

typedef _Float16 h8 __attribute__((ext_vector_type(8)));
typedef float fx4 __attribute__((ext_vector_type(4)));

__device__ __forceinline__ fx4 mfma16(h8 a, h8 b, fx4 c) {
    return __builtin_amdgcn_mfma_f32_16x16x32_f16(a, b, c, 0, 0, 0);
}
__device__ __forceinline__ float fast_tanh(float x) {
    float e = __expf(2.0f * x);
    return 1.0f - 2.0f / (e + 1.0f);
}
__device__ __forceinline__ float fast_sig(float x) { return 1.0f / (1.0f + __expf(-x)); }
__device__ __forceinline__ float lecun_tanh(float x) { return 1.7159f * fast_tanh(0.666f * x); }
__device__ __forceinline__ float softplus_f(float x) {
    return fmaxf(x, 0.0f) + __logf(1.0f + __expf(-fabsf(x)));
}

template <int NW>
__device__ __forceinline__ h8 loadB(const float* __restrict__ w, int col, int kbase) {
    h8 r;
#pragma unroll
    for (int j = 0; j < 8; ++j) r[j] = (_Float16)w[(kbase + j) * NW + col];
    return r;
}

__global__ void __launch_bounds__(512, 1) lh_scan_kernel(
    const float* __restrict__ x, const float* __restrict__ tsp, const float* __restrict__ hx,
    const float* __restrict__ w0, const float* __restrict__ b0,
    const float* __restrict__ w1, const float* __restrict__ b1,
    const float* __restrict__ f1w, const float* __restrict__ f1b,
    const float* __restrict__ f2w, const float* __restrict__ f2b,
    const float* __restrict__ taw, const float* __restrict__ tab,
    const float* __restrict__ tbw, const float* __restrict__ tbb,
    const float* __restrict__ pw, const float* __restrict__ pbias,
    const float* __restrict__ ihw0, const float* __restrict__ ihb0,
    const float* __restrict__ ihw1, const float* __restrict__ ihb1,
    const float* __restrict__ ahw0, const float* __restrict__ ahb0,
    const float* __restrict__ ahw1, const float* __restrict__ ahb1,
    const float* __restrict__ chw0, const float* __restrict__ chb0,
    const float* __restrict__ chw1, const float* __restrict__ chb1,
    float* __restrict__ out, unsigned int* __restrict__ flags,
    _Float16* __restrict__ hbuf)
{
    __shared__ __align__(16) _Float16 zin[16 * ZINS];
    __shared__ __align__(16) _Float16 z0b[16 * ZBS];
    __shared__ __align__(16) _Float16 z1b[16 * ZBS];
    __shared__ __align__(16) _Float16 cfcb[16 * CFS];
    __shared__ __align__(16) _Float16 pfl[8 * 4 * 64 * 8];   // proj B-frags: [kk][wv][lane][8]
    __shared__ __align__(16) _Float16 w1l[8 * 8 * 64 * 8];   // W1 cg1 B-frags: [kk][wv][lane][8]
    __shared__ __align__(16) float htmp[4 * 16 * HTS];
    __shared__ float hidI[16 * 16];
    __shared__ float hidA[16 * 16];
    __shared__ float hidC[16 * 8];
    __shared__ float tsb[2][16];
    __shared__ float wsm[80];

    const int tid  = threadIdx.x;
    const int wv   = tid >> 6;
    const int lane = tid & 63;
    const int lo   = lane & 15;
    const int hi   = lane >> 4;
    const int hi8  = hi * 8;
    const int losw = lo & 8;              // read-side swizzle bit (A rows = lo)

    const int bid   = blockIdx.x;
    const int xcd   = bid & 7;
    const int c     = (bid >> 3) & 7;     // column-slice id 0..7
    const int gsel  = bid >> 6;           // 0/1
    const int g     = xcd + 8 * gsel;     // batch group; 8 blocks of g share an XCD
    const int bg    = g * 16;
    const int sbase = c * 32;             // this block's 32 head columns

    // ---- small final-layer weights to LDS (all blocks) ----
    if (tid < 48)          wsm[tid] = ihw1[tid];
    else if (tid < 51)     wsm[tid] = ihb1[tid - 48];
    else if (tid < 67)     wsm[tid] = ahw1[tid - 51];
    else if (tid == 67)    wsm[67]  = ahb1[0];
    else if (tid < 76)     wsm[tid] = chw1[tid - 68];
    else if (tid == 76)    wsm[76]  = chb1[0];

    // ---- initial state (swizzled) ----
    {
        int r = tid >> 5, c8 = (tid & 31) * 8, sw = r & 8;
#pragma unroll
        for (int j = 0; j < 8; ++j)
            zin[r * ZINS + ((64 + c8 + j) ^ sw)] = (_Float16)hx[(bg + r) * HN + c8 + j];
        int c2 = (tid & 31) * 2;
        const float* xp = &x[((size_t)(bg + r) * SN + 0) * INN + c2];
        zin[r * ZINS + (c2 ^ sw)]       = (_Float16)xp[0];
        zin[r * ZINS + ((c2 + 1) ^ sw)] = (_Float16)xp[1];
    }
    if (tid < 16) tsb[0][tid] = tsp[(bg + tid) * SN + 0];

    // ---- per-lane column biases ----
    const int cg0 = wv, cg1 = wv + 8;
    const float b00 = b0[cg0 * 16 + lo], b01 = b0[cg1 * 16 + lo];
    const float b10 = b1[cg0 * 16 + lo], b11 = b1[cg1 * 16 + lo];

    const int hm  = wv >> 1;
    const int hcol = sbase + (wv & 1) * 16 + lo;
    const float* hwp = (hm == 0) ? f1w : (hm == 1) ? f2w : (hm == 2) ? taw : tbw;
    const float* hbp = (hm == 0) ? f1b : (hm == 1) ? f2b : (hm == 2) ? tab : tbb;
    const float hb = hbp[hcol];

    // ---- register-resident weight fragments (W0 both cgs, W1 cg0, head unit) ----
    h8 w0f0[10], w0f1[10], w1f0[8], hdf[8];
#pragma unroll
    for (int kk = 0; kk < 10; ++kk) {
        w0f0[kk] = loadB<256>(w0, cg0 * 16 + lo, kk * 32 + hi8);
        w0f1[kk] = loadB<256>(w0, cg1 * 16 + lo, kk * 32 + hi8);
    }
#pragma unroll
    for (int kk = 0; kk < 8; ++kk) {
        w1f0[kk] = loadB<256>(w1, cg0 * 16 + lo, kk * 32 + hi8);
        hdf[kk]  = loadB<256>(hwp, hcol, kk * 32 + hi8);
        h8 f = loadB<256>(w1, cg1 * 16 + lo, kk * 32 + hi8);
        *(h8*)&w1l[((kk * 8 + wv) * 64 + lane) * 8] = f;
    }
    // proj fragments -> LDS (ALL blocks now: proj duty rotates)
    float pbv = 0.0f;
    if (wv < 4) {
        pbv = pbias[wv * 16 + lo];
#pragma unroll
        for (int kk = 0; kk < 8; ++kk) {
            h8 f = loadB<64>(pw, wv * 16 + lo, kk * 32 + hi8);
            *(h8*)&pfl[((kk * 4 + wv) * 64 + lane) * 8] = f;
        }
    }
    h8 hwf[2] = {};
    float hbv = 0.0f;
    if (wv == 4) {
        hbv = ihb0[lo];
#pragma unroll
        for (int kk = 0; kk < 2; ++kk) hwf[kk] = loadB<16>(ihw0, lo, kk * 32 + hi8);
    } else if (wv == 5) {
        hbv = ahb0[lo];
#pragma unroll
        for (int kk = 0; kk < 2; ++kk) hwf[kk] = loadB<16>(ahw0, lo, kk * 32 + hi8);
    } else if (wv == 6) {
        int cc = (lo < 8) ? lo : 0;
        hbv = (lo < 8) ? chb0[lo] : 0.0f;
#pragma unroll
        for (int kk = 0; kk < 2; ++kk) hwf[kk] = loadB<8>(chw0, cc, kk * 32 + hi8);
    }

    __syncthreads();

    for (int t = 0; t <= SN; ++t) {
        const int pr = t & 7;   // which block does proj/outputs this step

        // ===== z0 = lecun([x|h] @ W0 + b0) =====
        if (t < SN) {
            fx4 a0 = {b00, b00, b00, b00}, a1 = {b01, b01, b01, b01};
#pragma unroll
            for (int kk = 0; kk < 10; ++kk) {
                h8 a = *(const h8*)&zin[lo * ZINS + ((kk * 32 + hi8) ^ losw)];
                a0 = mfma16(a, w0f0[kk], a0);
                a1 = mfma16(a, w0f1[kk], a1);
            }
#pragma unroll
            for (int i = 0; i < 4; ++i) {
                int r = hi * 4 + i, sw = r & 8;
                z0b[r * ZBS + ((cg0 * 16 + lo) ^ sw)] = (_Float16)lecun_tanh(a0[i]);
                z0b[r * ZBS + ((cg1 * 16 + lo) ^ sw)] = (_Float16)lecun_tanh(a1[i]);
            }
        }
        __syncthreads();  // S1

        // ===== z1 = lecun(z0 @ W1 + b1) =====
        if (t < SN) {
            fx4 a0 = {b10, b10, b10, b10}, a1 = {b11, b11, b11, b11};
#pragma unroll
            for (int kk = 0; kk < 8; ++kk) {
                h8 a = *(const h8*)&z0b[lo * ZBS + ((kk * 32 + hi8) ^ losw)];
                h8 b1f = *(const h8*)&w1l[((kk * 8 + wv) * 64 + lane) * 8];
                a0 = mfma16(a, w1f0[kk], a0);
                a1 = mfma16(a, b1f, a1);
            }
#pragma unroll
            for (int i = 0; i < 4; ++i) {
                int r = hi * 4 + i, sw = r & 8;
                z1b[r * ZBS + ((cg0 * 16 + lo) ^ sw)] = (_Float16)lecun_tanh(a0[i]);
                z1b[r * ZBS + ((cg1 * 16 + lo) ^ sw)] = (_Float16)lecun_tanh(a1[i]);
            }
        }
        __syncthreads();  // S2

        // ===== head unit: (matrix hm, colgroup wv&1) of this block's 32-col slice =====
        if (t < SN) {
            fx4 acc = {hb, hb, hb, hb};
#pragma unroll
            for (int kk = 0; kk < 8; ++kk) {
                h8 a = *(const h8*)&z1b[lo * ZBS + ((kk * 32 + hi8) ^ losw)];
                acc = mfma16(a, hdf[kk], acc);
            }
#pragma unroll
            for (int i = 0; i < 4; ++i)
                htmp[(hm * 16 + hi * 4 + i) * HTS + (wv & 1) * 16 + lo] = acc[i];
        }
        __syncthreads();  // S3

        // ===== combine -> h_new slice -> global hbuf =====
        if (t < SN) {
            int r = tid >> 5, cc = tid & 31;
            float a1v = htmp[(0 * 16 + r) * HTS + cc];
            float a2v = htmp[(1 * 16 + r) * HTS + cc];
            float a3v = htmp[(2 * 16 + r) * HTS + cc];
            float a4v = htmp[(3 * 16 + r) * HTS + cc];
            float tv  = tsb[t & 1][r];
            float ff1 = fast_tanh(a1v);
            float ff2 = fast_tanh(a2v);
            float ti  = fast_sig(a3v * tv + a4v);
            float hn  = ff1 + ti * (ff2 - ff1);
            hbuf[((((size_t)((t + 1) & 1) * 16 + g) * 16) + r) * 256 + sbase + cc] = (_Float16)hn;
            if (t == SN - 1) out[OFF_HN + (bg + r) * HN + sbase + cc] = hn;
        }
        __syncthreads();  // S4 (drains hbuf stores per-thread before epoch)
        if (t < SN && tid == 0)
            __hip_atomic_store(&flags[(g * 8 + c) * FLAG_STRIDE], (unsigned)(t + 1),
                               __ATOMIC_RELEASE, __HIP_MEMORY_SCOPE_AGENT);

        // ===== overlap phase: proj(t-1) on the rotating block; x/ts prefetch everywhere =====
        if (t >= 1 && c == pr && wv < 4) {
            fx4 acc = {pbv, pbv, pbv, pbv};
#pragma unroll
            for (int kk = 0; kk < 8; ++kk) {
                h8 a = *(const h8*)&zin[lo * ZINS + ((64 + kk * 32 + hi8) ^ losw)];
                h8 b = *(const h8*)&pfl[((kk * 4 + wv) * 64 + lane) * 8];
                acc = mfma16(a, b, acc);
            }
#pragma unroll
            for (int i = 0; i < 4; ++i) {
                int r = hi * 4 + i, sw = r & 8;
                cfcb[r * CFS + ((wv * 16 + lo) ^ sw)] = (_Float16)acc[i];
            }
        }
        if (t + 1 < SN) {
            int r = tid >> 5, c2 = (tid & 31) * 2, sw = r & 8;
            const float* xp = &x[((size_t)(bg + r) * SN + (t + 1)) * INN + c2];
            zin[r * ZINS + (c2 ^ sw)]       = (_Float16)xp[0];
            zin[r * ZINS + ((c2 + 1) ^ sw)] = (_Float16)xp[1];
            if (tid < 16) tsb[(t + 1) & 1][tid] = tsp[(bg + tid) * SN + t + 1];
        }
        __syncthreads();  // S5

        if (t >= 1 && c == pr && wv >= 4 && wv < 7) {
            fx4 acc = {hbv, hbv, hbv, hbv};
#pragma unroll
            for (int kk = 0; kk < 2; ++kk) {
                h8 a = *(const h8*)&cfcb[lo * CFS + ((kk * 32 + hi8) ^ losw)];
                acc = mfma16(a, hwf[kk], acc);
            }
#pragma unroll
            for (int i = 0; i < 4; ++i) {
                float v = acc[i];
                v = v * fast_sig(v);
                int r = hi * 4 + i;
                if (wv == 4)       hidI[r * 16 + lo] = v;
                else if (wv == 5)  hidA[r * 16 + lo] = v;
                else if (lo < 8)   hidC[r * 8 + lo]  = v;
            }
        }
        __syncthreads();  // S6

        if (t >= 1 && c == pr && tid < 80) {
            int r = tid / 5, o = tid % 5;
            int tc = t - 1;
            int b = bg + r;
            if (o < 3) {
                float s = wsm[48 + o];
#pragma unroll
                for (int u = 0; u < 16; ++u) s += hidI[r * 16 + u] * wsm[u * 3 + o];
                out[(size_t)(b * SN + tc) * 3 + o] = softplus_f(s);
            } else if (o == 3) {
                float s = wsm[67];
#pragma unroll
                for (int u = 0; u < 16; ++u) s += hidA[r * 16 + u] * wsm[51 + u];
                out[OFF_ACT + b * SN + tc] = fast_tanh(s);
            } else {
                float s = wsm[76];
#pragma unroll
                for (int u = 0; u < 8; ++u) s += hidC[r * 8 + u] * wsm[68 + u];
                out[OFF_CONF + b * SN + tc] = fast_sig(s);
            }
        }

        // ===== wait for all 8 blocks of the group (per-block epoch lines), reload h =====
        if (t < SN) {
            if (tid < 8) {
                unsigned target = (unsigned)(t + 1);
                while (__hip_atomic_load(&flags[(g * 8 + tid) * FLAG_STRIDE],
                                         __ATOMIC_ACQUIRE, __HIP_MEMORY_SCOPE_AGENT) < target) {}
            }
            __syncthreads();  // S7
            {
                int r = tid >> 5, c8 = (tid & 31) * 8, sw = r & 8;
                h8 hv = *(const h8*)&hbuf[((((size_t)((t + 1) & 1) * 16 + g) * 16) + r) * 256 + c8];
                *(h8*)&zin[r * ZINS + ((64 + c8) ^ sw)] = hv;
            }
        }
        __syncthreads();  // S8
    }
}

extern "C" void kernel_launch(void* const* d_in, const int* in_sizes, int n_in,
                              void* d_out, int out_size, void* d_ws, size_t ws_size,
                              hipStream_t stream) {
    (void)in_sizes; (void)n_in; (void)out_size; (void)ws_size;
    const float* p[29];
    for (int i = 0; i < 29; ++i) p[i] = (const float*)d_in[i];
    unsigned int* flags = (unsigned int*)d_ws;
    _Float16* hbuf = (_Float16*)((char*)d_ws + FLAG_BYTES);
    hipMemsetAsync(d_ws, 0, FLAG_BYTES, stream);
    hipLaunchKernelGGL(lh_scan_kernel, dim3(128), dim3(512), 0, stream,
        p[0], p[1], p[2], p[3], p[4], p[5], p[6], p[7], p[8], p[9], p[10], p[11], p[12],
        p[13], p[14], p[15], p[16], p[17], p[18], p[19], p[20], p[21], p[22], p[23],
        p[24], p[25], p[26], p[27], p[28], (float*)d_out, flags, hbuf);
}

// Round 6
// 2324.698 us; speedup vs baseline: 1.4202x; 1.4202x over previous
//
#include <hip/hip_runtime.h>
#include <hip/hip_bf16.h>

// Sizes (fixed by the reference)
#define BN  256
#define SN  512
#define INN 64
#define HN  256
#define MN  64

// LDS strides (f16 elems unless noted)
#define ZINS 328   // zin: [x(64) | h(256)] + 8 pad
#define ZBS  264   // z0/z1: 256 + 8
#define CFS  72    // cfc: 64 + 8
#define HTS  36    // htmp row stride (f32, 144B: 16B-aligned rows)

// Output offsets (f32 elements)
#define OFF_ACT  393216
#define OFF_CONF 524288
#define OFF_HN   655360

#define FLAG_STRIDE 32        // u32 per flag slot (128 B line spacing)
#define FLAG_BYTES  16384     // 16 groups * 8 blocks * 128 B

typedef _Float16 h8 __attribute__((ext_vector_type(8)));
typedef float fx4 __attribute__((ext_vector_type(4)));
typedef unsigned long long u64;

union h4u {
    _Float16 h[4];
    u64 u;
};

__device__ __forceinline__ fx4 mfma16(h8 a, h8 b, fx4 c) {
    return __builtin_amdgcn_mfma_f32_16x16x32_f16(a, b, c, 0, 0, 0);
}
__device__ __forceinline__ float fast_tanh(float x) {
    float e = __expf(2.0f * x);
    return 1.0f - 2.0f / (e + 1.0f);
}
__device__ __forceinline__ float fast_sig(float x) { return 1.0f / (1.0f + __expf(-x)); }
__device__ __forceinline__ float lecun_tanh(float x) { return 1.7159f * fast_tanh(0.666f * x); }
__device__ __forceinline__ float softplus_f(float x) {
    return fmaxf(x, 0.0f) + __logf(1.0f + __expf(-fabsf(x)));
}

template <int NW>
__device__ __forceinline__ h8 loadB(const float* __restrict__ w, int col, int kbase) {
    h8 r;
#pragma unroll
    for (int j = 0; j < 8; ++j) r[j] = (_Float16)w[(kbase + j) * NW + col];
    return r;
}

__global__ void __launch_bounds__(512, 1) lh_scan_kernel(
    const float* __restrict__ x, const float* __restrict__ tsp, const float* __restrict__ hx,
    const float* __restrict__ w0, const float* __restrict__ b0,
    const float* __restrict__ w1, const float* __restrict__ b1,
    const float* __restrict__ f1w, const float* __restrict__ f1b,
    const float* __restrict__ f2w, const float* __restrict__ f2b,
    const float* __restrict__ taw, const float* __restrict__ tab,
    const float* __restrict__ tbw, const float* __restrict__ tbb,
    const float* __restrict__ pw, const float* __restrict__ pbias,
    const float* __restrict__ ihw0, const float* __restrict__ ihb0,
    const float* __restrict__ ihw1, const float* __restrict__ ihb1,
    const float* __restrict__ ahw0, const float* __restrict__ ahb0,
    const float* __restrict__ ahw1, const float* __restrict__ ahb1,
    const float* __restrict__ chw0, const float* __restrict__ chb0,
    const float* __restrict__ chw1, const float* __restrict__ chb1,
    float* __restrict__ out, unsigned int* __restrict__ flags,
    u64* __restrict__ hbuf)
{
    __shared__ __align__(16) _Float16 zin[16 * ZINS];
    __shared__ __align__(16) _Float16 z0b[16 * ZBS];
    __shared__ __align__(16) _Float16 z1b[16 * ZBS];
    __shared__ __align__(16) _Float16 cfcb[16 * CFS];
    __shared__ __align__(16) _Float16 pfl[8 * 4 * 64 * 8];   // proj B-frags
    __shared__ __align__(16) _Float16 w1l[8 * 8 * 64 * 8];   // W1 cg1 B-frags
    __shared__ __align__(16) float htmp[4 * 16 * HTS];
    __shared__ float hidI[16 * 16];
    __shared__ float hidA[16 * 16];
    __shared__ float hidC[16 * 8];
    __shared__ float tsb[2][16];
    __shared__ float wsm[80];

    const int tid  = threadIdx.x;
    const int wv   = tid >> 6;
    const int lane = tid & 63;
    const int lo   = lane & 15;
    const int hi   = lane >> 4;
    const int hi8  = hi * 8;

    const int bid   = blockIdx.x;
    const int xcd   = bid & 7;
    const int c     = (bid >> 3) & 7;     // column-slice id 0..7
    const int gsel  = bid >> 6;           // 0/1
    const int g     = xcd + 8 * gsel;     // batch group; 8 blocks of g share an XCD
    const int bg    = g * 16;
    const int sbase = c * 32;             // this block's 32 head columns

    // ---- small final-layer weights to LDS ----
    if (tid < 48)          wsm[tid] = ihw1[tid];
    else if (tid < 51)     wsm[tid] = ihb1[tid - 48];
    else if (tid < 67)     wsm[tid] = ahw1[tid - 51];
    else if (tid == 67)    wsm[67]  = ahb1[0];
    else if (tid < 76)     wsm[tid] = chw1[tid - 68];
    else if (tid == 76)    wsm[76]  = chb1[0];

    // ---- initial state ----
    {
        int r = tid >> 5, c8 = (tid & 31) * 8;
#pragma unroll
        for (int j = 0; j < 8; ++j)
            zin[r * ZINS + 64 + c8 + j] = (_Float16)hx[(bg + r) * HN + c8 + j];
        int c2 = (tid & 31) * 2;
        const float* xp = &x[((size_t)(bg + r) * SN + 0) * INN + c2];
        zin[r * ZINS + c2]     = (_Float16)xp[0];
        zin[r * ZINS + c2 + 1] = (_Float16)xp[1];
    }
    if (tid < 16) tsb[0][tid] = tsp[(bg + tid) * SN + 0];

    // ---- per-lane column biases ----
    const int cg0 = wv, cg1 = wv + 8;
    const float b00 = b0[cg0 * 16 + lo], b01 = b0[cg1 * 16 + lo];
    const float b10 = b1[cg0 * 16 + lo], b11 = b1[cg1 * 16 + lo];

    const int hm  = wv >> 1;
    const int hcol = sbase + (wv & 1) * 16 + lo;
    const float* hwp = (hm == 0) ? f1w : (hm == 1) ? f2w : (hm == 2) ? taw : tbw;
    const float* hbp = (hm == 0) ? f1b : (hm == 1) ? f2b : (hm == 2) ? tab : tbb;
    const float hb = hbp[hcol];

    // ---- register-resident weight fragments (W0 both cgs, W1 cg0, head unit) ----
    h8 w0f0[10], w0f1[10], w1f0[8], hdf[8];
#pragma unroll
    for (int kk = 0; kk < 10; ++kk) {
        w0f0[kk] = loadB<256>(w0, cg0 * 16 + lo, kk * 32 + hi8);
        w0f1[kk] = loadB<256>(w0, cg1 * 16 + lo, kk * 32 + hi8);
    }
#pragma unroll
    for (int kk = 0; kk < 8; ++kk) {
        w1f0[kk] = loadB<256>(w1, cg0 * 16 + lo, kk * 32 + hi8);
        hdf[kk]  = loadB<256>(hwp, hcol, kk * 32 + hi8);
        h8 f = loadB<256>(w1, cg1 * 16 + lo, kk * 32 + hi8);
        *(h8*)&w1l[((kk * 8 + wv) * 64 + lane) * 8] = f;
    }
    // proj fragments -> LDS (all blocks: proj duty rotates)
    float pbv = 0.0f;
    if (wv < 4) {
        pbv = pbias[wv * 16 + lo];
#pragma unroll
        for (int kk = 0; kk < 8; ++kk) {
            h8 f = loadB<64>(pw, wv * 16 + lo, kk * 32 + hi8);
            *(h8*)&pfl[((kk * 4 + wv) * 64 + lane) * 8] = f;
        }
    }
    h8 hwf[2] = {};
    float hbv = 0.0f;
    if (wv == 4) {
        hbv = ihb0[lo];
#pragma unroll
        for (int kk = 0; kk < 2; ++kk) hwf[kk] = loadB<16>(ihw0, lo, kk * 32 + hi8);
    } else if (wv == 5) {
        hbv = ahb0[lo];
#pragma unroll
        for (int kk = 0; kk < 2; ++kk) hwf[kk] = loadB<16>(ahw0, lo, kk * 32 + hi8);
    } else if (wv == 6) {
        int cc = (lo < 8) ? lo : 0;
        hbv = (lo < 8) ? chb0[lo] : 0.0f;
#pragma unroll
        for (int kk = 0; kk < 2; ++kk) hwf[kk] = loadB<8>(chw0, cc, kk * 32 + hi8);
    }

    __syncthreads();

    for (int t = 0; t <= SN; ++t) {
        const int pr = t & 7;   // which block does proj/outputs this step

        // ===== z0 = lecun([x|h] @ W0 + b0) =====
        if (t < SN) {
            fx4 a0 = {b00, b00, b00, b00}, a1 = {b01, b01, b01, b01};
#pragma unroll
            for (int kk = 0; kk < 10; ++kk) {
                h8 a = *(const h8*)&zin[lo * ZINS + kk * 32 + hi8];
                a0 = mfma16(a, w0f0[kk], a0);
                a1 = mfma16(a, w0f1[kk], a1);
            }
#pragma unroll
            for (int i = 0; i < 4; ++i) {
                int r = hi * 4 + i;
                z0b[r * ZBS + cg0 * 16 + lo] = (_Float16)lecun_tanh(a0[i]);
                z0b[r * ZBS + cg1 * 16 + lo] = (_Float16)lecun_tanh(a1[i]);
            }
        }
        __syncthreads();  // S1

        // x/ts prefetch for t+1 (zin x-region is free now; overlaps z1/head phases)
        if (t + 1 < SN) {
            int r = tid >> 5, c2 = (tid & 31) * 2;
            const float* xp = &x[((size_t)(bg + r) * SN + (t + 1)) * INN + c2];
            zin[r * ZINS + c2]     = (_Float16)xp[0];
            zin[r * ZINS + c2 + 1] = (_Float16)xp[1];
            if (tid < 16) tsb[(t + 1) & 1][tid] = tsp[(bg + tid) * SN + t + 1];
        }

        // ===== z1 = lecun(z0 @ W1 + b1) =====
        if (t < SN) {
            fx4 a0 = {b10, b10, b10, b10}, a1 = {b11, b11, b11, b11};
#pragma unroll
            for (int kk = 0; kk < 8; ++kk) {
                h8 a = *(const h8*)&z0b[lo * ZBS + kk * 32 + hi8];
                h8 b1f = *(const h8*)&w1l[((kk * 8 + wv) * 64 + lane) * 8];
                a0 = mfma16(a, w1f0[kk], a0);
                a1 = mfma16(a, b1f, a1);
            }
#pragma unroll
            for (int i = 0; i < 4; ++i) {
                int r = hi * 4 + i;
                z1b[r * ZBS + cg0 * 16 + lo] = (_Float16)lecun_tanh(a0[i]);
                z1b[r * ZBS + cg1 * 16 + lo] = (_Float16)lecun_tanh(a1[i]);
            }
        }
        __syncthreads();  // S2

        // ===== head unit: (matrix hm, colgroup wv&1) of this block's 32-col slice =====
        if (t < SN) {
            fx4 acc = {hb, hb, hb, hb};
#pragma unroll
            for (int kk = 0; kk < 8; ++kk) {
                h8 a = *(const h8*)&z1b[lo * ZBS + kk * 32 + hi8];
                acc = mfma16(a, hdf[kk], acc);
            }
#pragma unroll
            for (int i = 0; i < 4; ++i)
                htmp[(hm * 16 + hi * 4 + i) * HTS + (wv & 1) * 16 + lo] = acc[i];
        }
        __syncthreads();  // S3

        // ===== combine -> h_new slice (4 cols/thread) -> coherent u64 store =====
        if (t < SN && tid < 128) {
            int r = tid >> 3, c4 = (tid & 7) * 4;
            h4u pk;
            float hn3 = 0.0f;
#pragma unroll
            for (int k = 0; k < 4; ++k) {
                float a1v = htmp[(0 * 16 + r) * HTS + c4 + k];
                float a2v = htmp[(1 * 16 + r) * HTS + c4 + k];
                float a3v = htmp[(2 * 16 + r) * HTS + c4 + k];
                float a4v = htmp[(3 * 16 + r) * HTS + c4 + k];
                float tv  = tsb[t & 1][r];
                float ff1 = fast_tanh(a1v);
                float ff2 = fast_tanh(a2v);
                float ti  = fast_sig(a3v * tv + a4v);
                float hn  = ff1 + ti * (ff2 - ff1);
                pk.h[k] = (_Float16)hn;
                if (t == SN - 1) out[OFF_HN + (bg + r) * HN + sbase + c4 + k] = hn;
                hn3 = hn;
            }
            (void)hn3;
            size_t idx = ((((size_t)((t + 1) & 1) * 16 + g) * 16) + r) * 64 + (sbase + c4) / 4;
            __hip_atomic_store(&hbuf[idx], pk.u, __ATOMIC_RELAXED, __HIP_MEMORY_SCOPE_AGENT);
        }
        __syncthreads();  // S4 (all waves' vmcnt drained -> h slice at coherence point)
        if (t < SN && tid == 0)
            __hip_atomic_store(&flags[(g * 8 + c) * FLAG_STRIDE], (unsigned)(t + 1),
                               __ATOMIC_RELAXED, __HIP_MEMORY_SCOPE_AGENT);

        // ===== overlap: proj(t-1) on the rotating block =====
        if (t >= 1 && c == pr && wv < 4) {
            fx4 acc = {pbv, pbv, pbv, pbv};
#pragma unroll
            for (int kk = 0; kk < 8; ++kk) {
                h8 a = *(const h8*)&zin[lo * ZINS + 64 + kk * 32 + hi8];
                h8 b = *(const h8*)&pfl[((kk * 4 + wv) * 64 + lane) * 8];
                acc = mfma16(a, b, acc);
            }
#pragma unroll
            for (int i = 0; i < 4; ++i)
                cfcb[(hi * 4 + i) * CFS + wv * 16 + lo] = (_Float16)acc[i];
        }
        __syncthreads();  // S5

        if (t >= 1 && c == pr && wv >= 4 && wv < 7) {
            fx4 acc = {hbv, hbv, hbv, hbv};
#pragma unroll
            for (int kk = 0; kk < 2; ++kk) {
                h8 a = *(const h8*)&cfcb[lo * CFS + kk * 32 + hi8];
                acc = mfma16(a, hwf[kk], acc);
            }
#pragma unroll
            for (int i = 0; i < 4; ++i) {
                float v = acc[i];
                v = v * fast_sig(v);
                int r = hi * 4 + i;
                if (wv == 4)       hidI[r * 16 + lo] = v;
                else if (wv == 5)  hidA[r * 16 + lo] = v;
                else if (lo < 8)   hidC[r * 8 + lo]  = v;
            }
        }
        __syncthreads();  // S6

        if (t >= 1 && c == pr && tid < 80) {
            int r = tid / 5, o = tid % 5;
            int tc = t - 1;
            int b = bg + r;
            if (o < 3) {
                float s = wsm[48 + o];
#pragma unroll
                for (int u = 0; u < 16; ++u) s += hidI[r * 16 + u] * wsm[u * 3 + o];
                out[(size_t)(b * SN + tc) * 3 + o] = softplus_f(s);
            } else if (o == 3) {
                float s = wsm[67];
#pragma unroll
                for (int u = 0; u < 16; ++u) s += hidA[r * 16 + u] * wsm[51 + u];
                out[OFF_ACT + b * SN + tc] = fast_tanh(s);
            } else {
                float s = wsm[76];
#pragma unroll
                for (int u = 0; u < 8; ++u) s += hidC[r * 8 + u] * wsm[68 + u];
                out[OFF_CONF + b * SN + tc] = fast_sig(s);
            }
        }

        // ===== wait for all 8 blocks of the group (relaxed poll), coherent h reload =====
        if (t < SN) {
            if (tid < 8) {
                unsigned target = (unsigned)(t + 1);
                while (__hip_atomic_load(&flags[(g * 8 + tid) * FLAG_STRIDE],
                                         __ATOMIC_RELAXED, __HIP_MEMORY_SCOPE_AGENT) < target) {}
            }
            __syncthreads();  // S7
            {
                int r = tid >> 5, c8 = (tid & 31) * 8;
                size_t idx = ((((size_t)((t + 1) & 1) * 16 + g) * 16) + r) * 64 + c8 / 4;
                u64 v0 = __hip_atomic_load(&hbuf[idx],     __ATOMIC_RELAXED, __HIP_MEMORY_SCOPE_AGENT);
                u64 v1 = __hip_atomic_load(&hbuf[idx + 1], __ATOMIC_RELAXED, __HIP_MEMORY_SCOPE_AGENT);
                *(u64*)&zin[r * ZINS + 64 + c8]     = v0;
                *(u64*)&zin[r * ZINS + 64 + c8 + 4] = v1;
            }
        }
        __syncthreads();  // S8
    }
}

extern "C" void kernel_launch(void* const* d_in, const int* in_sizes, int n_in,
                              void* d_out, int out_size, void* d_ws, size_t ws_size,
                              hipStream_t stream) {
    (void)in_sizes; (void)n_in; (void)out_size; (void)ws_size;
    const float* p[29];
    for (int i = 0; i < 29; ++i) p[i] = (const float*)d_in[i];
    unsigned int* flags = (unsigned int*)d_ws;
    u64* hbuf = (u64*)((char*)d_ws + FLAG_BYTES);
    hipMemsetAsync(d_ws, 0, FLAG_BYTES, stream);
    hipLaunchKernelGGL(lh_scan_kernel, dim3(128), dim3(512), 0, stream,
        p[0], p[1], p[2], p[3], p[4], p[5], p[6], p[7], p[8], p[9], p[10], p[11], p[12],
        p[13], p[14], p[15], p[16], p[17], p[18], p[19], p[20], p[21], p[22], p[23],
        p[24], p[25], p[26], p[27], p[28], (float*)d_out, flags, hbuf);
}